// Round 2
// baseline (316.146 us; speedup 1.0000x reference)
//
#include <hip/hip_runtime.h>
#include <math.h>

#define P_NUM 8192
#define E_NUM 4194304

__global__ __launch_bounds__(256) void ba_kernel(
    const float* __restrict__ poses,        // P_NUM*7
    const float* __restrict__ init_poses,   // P_NUM*7
    const float* __restrict__ patch_coords, // E_NUM*2  (r, theta)
    const float* __restrict__ elev,         // E_NUM
    const float* __restrict__ init_elev,    // E_NUM
    const float* __restrict__ target,       // E_NUM*2
    const int*   __restrict__ src_idx,
    const int*   __restrict__ tgt_idx,
    const int*   __restrict__ patch_idx,
    float*       __restrict__ out)
{
    const int i = blockIdx.x * blockDim.x + threadIdx.x;
    if (i >= E_NUM) return;

    const float R_RANGE = 30.0f - 0.5f;     // R_MAX - R_MIN
    const float BINS    = 512.0f;
    const float BEAMS   = 512.0f;
    const float FOV_H   = 2.0943951f;

    const int s = src_idx[i];
    const int t = tgt_idx[i];
    const int p = patch_idx[i];

    // gathered patch data
    const float2 pc = ((const float2*)patch_coords)[p];
    const float  ph = elev[p];
    const float  r  = pc.x;
    const float  th = pc.y;

    // polar2cart
    const float cp  = cosf(ph), sph = sinf(ph);
    const float ct  = cosf(th), sth = sinf(th);
    float vx = r * cp * ct;
    float vy = r * cp * sth;
    float vz = r * sph;

    // src pose (poses fully cached in L2: 8192*7*4 = 229 KB)
    const float* sp = poses + 7 * s;
    const float stx = sp[0], sty = sp[1], stz = sp[2];
    float ux = sp[3], uy = sp[4], uz = sp[5], uw = sp[6];

    // quat rotate: tq = 2*cross(u,v); res = v + w*tq + cross(u,tq)
    float tqx = 2.0f * (uy * vz - uz * vy);
    float tqy = 2.0f * (uz * vx - ux * vz);
    float tqz = 2.0f * (ux * vy - uy * vx);
    float gx = vx + uw * tqx + (uy * tqz - uz * tqy) + stx;
    float gy = vy + uw * tqy + (uz * tqx - ux * tqz) + sty;
    float gz = vz + uw * tqz + (ux * tqy - uy * tqx) + stz;

    // tgt pose, inverse quat rotate
    const float* tp = poses + 7 * t;
    const float ttx = tp[0], tty = tp[1], ttz = tp[2];
    ux = -tp[3]; uy = -tp[4]; uz = -tp[5]; uw = tp[6];
    vx = gx - ttx; vy = gy - tty; vz = gz - ttz;

    tqx = 2.0f * (uy * vz - uz * vy);
    tqy = 2.0f * (uz * vx - ux * vz);
    tqz = 2.0f * (ux * vy - uy * vx);
    const float lx = vx + uw * tqx + (uy * tqz - uz * tqy);
    const float ly = vy + uw * tqy + (uz * tqx - ux * tqz);
    const float lz = vz + uw * tqz + (ux * tqy - uy * tqx);

    // cart2polar -> only r and theta are used downstream
    const float rr  = sqrtf(lx * lx + ly * ly + lz * lz);
    const float tth = atan2f(ly, lx);

    const float2 tg = ((const float2*)target)[i];
    const float err_r = (rr  - tg.x) / R_RANGE * BINS;
    const float err_t = (tth - tg.y) / FOV_H * BEAMS;

    // residual_proj: out[2*i], out[2*i+1]
    float2 o; o.x = err_r; o.y = err_t;
    ((float2*)out)[i] = o;

    // residual_pose: 7*P_NUM = 57344 elements, handled by first threads
    if (i < 7 * P_NUM) {
        out[2 * E_NUM + i] = poses[i] - init_poses[i];
    }

    // residual_elev: sequential
    out[2 * E_NUM + 7 * P_NUM + i] = elev[i] - init_elev[i];
}

extern "C" void kernel_launch(void* const* d_in, const int* in_sizes, int n_in,
                              void* d_out, int out_size, void* d_ws, size_t ws_size,
                              hipStream_t stream) {
    const float* poses        = (const float*)d_in[0];
    const float* init_poses   = (const float*)d_in[1];
    const float* patch_coords = (const float*)d_in[2];
    const float* elev         = (const float*)d_in[3];
    const float* init_elev    = (const float*)d_in[4];
    const float* target       = (const float*)d_in[5];
    const int*   src_idx      = (const int*)d_in[6];
    const int*   tgt_idx      = (const int*)d_in[7];
    const int*   patch_idx    = (const int*)d_in[8];
    float*       out          = (float*)d_out;

    const int block = 256;
    const int grid  = (E_NUM + block - 1) / block;
    ba_kernel<<<grid, block, 0, stream>>>(poses, init_poses, patch_coords, elev,
                                          init_elev, target, src_idx, tgt_idx,
                                          patch_idx, out);
}

// Round 3
// 312.325 us; speedup vs baseline: 1.0122x; 1.0122x over previous
//
#include <hip/hip_runtime.h>
#include <math.h>

#define P_NUM 8192
#define E_NUM 4194304
#define EPT 4

// ---------- prep: pad poses 7 -> 8 floats so a pose is 2x float4 ----------
__global__ __launch_bounds__(256) void pose_pad_kernel(const float* __restrict__ poses,
                                                       float* __restrict__ pose8) {
    int p = blockIdx.x * blockDim.x + threadIdx.x;
    if (p >= P_NUM) return;
    const float* s = poses + 7 * p;
    float4 lo = make_float4(s[0], s[1], s[2], s[3]);   // tx ty tz qx
    float4 hi = make_float4(s[4], s[5], s[6], 0.0f);   // qy qz qw pad
    ((float4*)pose8)[2 * p]     = lo;
    ((float4*)pose8)[2 * p + 1] = hi;
}

__device__ __forceinline__ void quatrot(float ux, float uy, float uz, float uw,
                                        float vx, float vy, float vz,
                                        float& ox, float& oy, float& oz) {
    float tqx = 2.0f * (uy * vz - uz * vy);
    float tqy = 2.0f * (uz * vx - ux * vz);
    float tqz = 2.0f * (ux * vy - uy * vx);
    ox = vx + uw * tqx + (uy * tqz - uz * tqy);
    oy = vy + uw * tqy + (uz * tqx - ux * tqz);
    oz = vz + uw * tqz + (ux * tqy - uy * tqx);
}

__global__ __launch_bounds__(256) void ba_main(
    const float* __restrict__ poses,        // original, for pose residual
    const float* __restrict__ init_poses,
    const float* __restrict__ pose8,        // padded poses in ws
    const float* __restrict__ patch_coords, // E_NUM*2
    const float* __restrict__ elev,         // E_NUM
    const float* __restrict__ init_elev,    // E_NUM
    const float* __restrict__ target,       // E_NUM*2
    const int*   __restrict__ src_idx,
    const int*   __restrict__ tgt_idx,
    const int*   __restrict__ patch_idx,
    float*       __restrict__ out)
{
    const int tid = blockIdx.x * blockDim.x + threadIdx.x;  // [0, E_NUM/EPT)

    const float R_RANGE = 30.0f - 0.5f;
    const float BINS    = 512.0f;
    const float BEAMS   = 512.0f;
    const float FOV_H   = 2.0943951f;

    // ---- index loads: coalesced int4 ----
    const int4 s4 = ((const int4*)src_idx)[tid];
    const int4 t4 = ((const int4*)tgt_idx)[tid];
    const int4 p4 = ((const int4*)patch_idx)[tid];
    const int si[EPT] = {s4.x, s4.y, s4.z, s4.w};
    const int ti[EPT] = {t4.x, t4.y, t4.z, t4.w};
    const int pi[EPT] = {p4.x, p4.y, p4.z, p4.w};

    // ---- issue ALL gathers up front (independent -> high MLP) ----
    float2 pc[EPT];
    float  ph[EPT];
    float4 slo[EPT], shi[EPT], tlo[EPT], thi[EPT];
    const float2* pcv  = (const float2*)patch_coords;
    const float4* p8v  = (const float4*)pose8;
#pragma unroll
    for (int e = 0; e < EPT; ++e) {
        pc[e]  = pcv[pi[e]];
        ph[e]  = elev[pi[e]];
        slo[e] = p8v[2 * si[e]];
        shi[e] = p8v[2 * si[e] + 1];
        tlo[e] = p8v[2 * ti[e]];
        thi[e] = p8v[2 * ti[e] + 1];
    }

    // sequential inputs
    const float4 tg01 = ((const float4*)target)[2 * tid];      // edges 0,1
    const float4 tg23 = ((const float4*)target)[2 * tid + 1];  // edges 2,3
    const float tgr[EPT] = {tg01.x, tg01.z, tg23.x, tg23.z};
    const float tgt_[EPT] = {tg01.y, tg01.w, tg23.y, tg23.w};
    const float4 ev  = ((const float4*)elev)[tid];
    const float4 iev = ((const float4*)init_elev)[tid];

    float res[2 * EPT];
#pragma unroll
    for (int e = 0; e < EPT; ++e) {
        const float r  = pc[e].x;
        const float th = pc[e].y;
        const float cp = cosf(ph[e]), sph = sinf(ph[e]);
        const float ct = cosf(th),    sth = sinf(th);
        float vx = r * cp * ct;
        float vy = r * cp * sth;
        float vz = r * sph;

        // rotate into world by src quat, translate
        float gx, gy, gz;
        quatrot(slo[e].w, shi[e].x, shi[e].y, shi[e].z, vx, vy, vz, gx, gy, gz);
        gx += slo[e].x; gy += slo[e].y; gz += slo[e].z;

        // inverse-rotate into tgt frame
        float lx, ly, lz;
        quatrot(-tlo[e].w, -thi[e].x, -thi[e].y, thi[e].z,
                gx - tlo[e].x, gy - tlo[e].y, gz - tlo[e].z, lx, ly, lz);

        const float rr  = sqrtf(lx * lx + ly * ly + lz * lz);
        const float tth = atan2f(ly, lx);
        res[2 * e]     = (rr  - tgr[e])  / R_RANGE * BINS;
        res[2 * e + 1] = (tth - tgt_[e]) / FOV_H * BEAMS;
    }

    // ---- stores ----
    float4* outv = (float4*)out;
    outv[2 * tid]     = make_float4(res[0], res[1], res[2], res[3]);
    outv[2 * tid + 1] = make_float4(res[4], res[5], res[6], res[7]);

    // residual_elev (sequential float4)
    ((float4*)(out + 2 * E_NUM + 7 * P_NUM))[tid] =
        make_float4(ev.x - iev.x, ev.y - iev.y, ev.z - iev.z, ev.w - iev.w);

    // residual_pose: 7*P_NUM = 57344 floats = 14336 float4s
    if (tid < (7 * P_NUM) / 4) {
        const float4 a = ((const float4*)poses)[tid];
        const float4 b = ((const float4*)init_poses)[tid];
        ((float4*)(out + 2 * E_NUM))[tid] =
            make_float4(a.x - b.x, a.y - b.y, a.z - b.z, a.w - b.w);
    }
}

extern "C" void kernel_launch(void* const* d_in, const int* in_sizes, int n_in,
                              void* d_out, int out_size, void* d_ws, size_t ws_size,
                              hipStream_t stream) {
    const float* poses        = (const float*)d_in[0];
    const float* init_poses   = (const float*)d_in[1];
    const float* patch_coords = (const float*)d_in[2];
    const float* elev         = (const float*)d_in[3];
    const float* init_elev    = (const float*)d_in[4];
    const float* target       = (const float*)d_in[5];
    const int*   src_idx      = (const int*)d_in[6];
    const int*   tgt_idx      = (const int*)d_in[7];
    const int*   patch_idx    = (const int*)d_in[8];
    float*       out          = (float*)d_out;
    float*       pose8        = (float*)d_ws;   // needs 8192*8*4 = 256 KB

    pose_pad_kernel<<<(P_NUM + 255) / 256, 256, 0, stream>>>(poses, pose8);

    const int block = 256;
    const int grid  = E_NUM / (block * EPT);    // 4096, exact
    ba_main<<<grid, block, 0, stream>>>(poses, init_poses, pose8, patch_coords,
                                        elev, init_elev, target, src_idx,
                                        tgt_idx, patch_idx, out);
}

// Round 4
// 277.702 us; speedup vs baseline: 1.1384x; 1.1247x over previous
//
#include <hip/hip_runtime.h>
#include <math.h>

#define P_NUM 8192
#define E_NUM 4194304
#define EPT 4

// ---------- prep A: fuse (r, theta, elev) into one float4 gather table ----------
__global__ __launch_bounds__(256) void fuse_prep(const float* __restrict__ patch_coords,
                                                 const float* __restrict__ elev,
                                                 float4* __restrict__ fused) {
    const int tid = blockIdx.x * blockDim.x + threadIdx.x;   // [0, E_NUM/4)
    const float4 a = ((const float4*)patch_coords)[2 * tid];     // (r0,t0,r1,t1)
    const float4 b = ((const float4*)patch_coords)[2 * tid + 1]; // (r2,t2,r3,t3)
    const float4 e = ((const float4*)elev)[tid];
    fused[4 * tid + 0] = make_float4(a.x, a.y, e.x, 0.0f);
    fused[4 * tid + 1] = make_float4(a.z, a.w, e.y, 0.0f);
    fused[4 * tid + 2] = make_float4(b.x, b.y, e.z, 0.0f);
    fused[4 * tid + 3] = make_float4(b.z, b.w, e.w, 0.0f);
}

// ---------- prep B: pad poses 7->8 floats + pose residual ----------
__global__ __launch_bounds__(256) void pose_prep(const float* __restrict__ poses,
                                                 const float* __restrict__ init_poses,
                                                 float4* __restrict__ pose8,
                                                 float* __restrict__ out) {
    const int tid = blockIdx.x * blockDim.x + threadIdx.x;   // [0, 14336)
    if (tid < P_NUM) {
        const float* s = poses + 7 * tid;
        pose8[2 * tid]     = make_float4(s[0], s[1], s[2], s[3]);  // tx ty tz qx
        pose8[2 * tid + 1] = make_float4(s[4], s[5], s[6], 0.0f);  // qy qz qw pad
    }
    if (tid < (7 * P_NUM) / 4) {
        const float4 a = ((const float4*)poses)[tid];
        const float4 b = ((const float4*)init_poses)[tid];
        ((float4*)(out + 2 * E_NUM))[tid] =
            make_float4(a.x - b.x, a.y - b.y, a.z - b.z, a.w - b.w);
    }
}

__device__ __forceinline__ void quatrot(float ux, float uy, float uz, float uw,
                                        float vx, float vy, float vz,
                                        float& ox, float& oy, float& oz) {
    float tqx = 2.0f * (uy * vz - uz * vy);
    float tqy = 2.0f * (uz * vx - ux * vz);
    float tqz = 2.0f * (ux * vy - uy * vx);
    ox = vx + uw * tqx + (uy * tqz - uz * tqy);
    oy = vy + uw * tqy + (uz * tqx - ux * tqz);
    oz = vz + uw * tqz + (ux * tqy - uy * tqx);
}

template <bool FUSED>
__global__ __launch_bounds__(256) void ba_main(
    const float4* __restrict__ fused,       // E_NUM x (r,theta,elev,pad), ws
    const float*  __restrict__ patch_coords,// fallback path
    const float*  __restrict__ elev,        // E_NUM (also sequential residual)
    const float*  __restrict__ init_elev,   // E_NUM
    const float4* __restrict__ pose8,       // ws
    const float*  __restrict__ target,      // E_NUM*2
    const int*    __restrict__ src_idx,
    const int*    __restrict__ tgt_idx,
    const int*    __restrict__ patch_idx,
    float*        __restrict__ out)
{
    const int tid = blockIdx.x * blockDim.x + threadIdx.x;  // [0, E_NUM/EPT)

    const float R_RANGE = 30.0f - 0.5f;
    const float BINS    = 512.0f;
    const float BEAMS   = 512.0f;
    const float FOV_H   = 2.0943951f;

    const int4 s4 = ((const int4*)src_idx)[tid];
    const int4 t4 = ((const int4*)tgt_idx)[tid];
    const int4 p4 = ((const int4*)patch_idx)[tid];
    const int si[EPT] = {s4.x, s4.y, s4.z, s4.w};
    const int ti[EPT] = {t4.x, t4.y, t4.z, t4.w};
    const int pi[EPT] = {p4.x, p4.y, p4.z, p4.w};

    // ---- issue all gathers up front ----
    float pr[EPT], pth[EPT], pph[EPT];
    float4 slo[EPT], shi[EPT], tlo[EPT], thi[EPT];
#pragma unroll
    for (int e = 0; e < EPT; ++e) {
        if (FUSED) {
            const float4 f = fused[pi[e]];
            pr[e] = f.x; pth[e] = f.y; pph[e] = f.z;
        } else {
            const float2 pc = ((const float2*)patch_coords)[pi[e]];
            pr[e] = pc.x; pth[e] = pc.y; pph[e] = elev[pi[e]];
        }
        slo[e] = pose8[2 * si[e]];
        shi[e] = pose8[2 * si[e] + 1];
        tlo[e] = pose8[2 * ti[e]];
        thi[e] = pose8[2 * ti[e] + 1];
    }

    const float4 tg01 = ((const float4*)target)[2 * tid];
    const float4 tg23 = ((const float4*)target)[2 * tid + 1];
    const float tgr[EPT]  = {tg01.x, tg01.z, tg23.x, tg23.z};
    const float tgth[EPT] = {tg01.y, tg01.w, tg23.y, tg23.w};
    const float4 ev  = ((const float4*)elev)[tid];
    const float4 iev = ((const float4*)init_elev)[tid];

    float res[2 * EPT];
#pragma unroll
    for (int e = 0; e < EPT; ++e) {
        const float r  = pr[e];
        const float cp = cosf(pph[e]), sph = sinf(pph[e]);
        const float ct = cosf(pth[e]), sth = sinf(pth[e]);
        float vx = r * cp * ct;
        float vy = r * cp * sth;
        float vz = r * sph;

        float gx, gy, gz;
        quatrot(slo[e].w, shi[e].x, shi[e].y, shi[e].z, vx, vy, vz, gx, gy, gz);
        gx += slo[e].x; gy += slo[e].y; gz += slo[e].z;

        float lx, ly, lz;
        quatrot(-tlo[e].w, -thi[e].x, -thi[e].y, thi[e].z,
                gx - tlo[e].x, gy - tlo[e].y, gz - tlo[e].z, lx, ly, lz);

        const float rr  = sqrtf(lx * lx + ly * ly + lz * lz);
        const float tth = atan2f(ly, lx);
        res[2 * e]     = (rr  - tgr[e])  / R_RANGE * BINS;
        res[2 * e + 1] = (tth - tgth[e]) / FOV_H * BEAMS;
    }

    float4* outv = (float4*)out;
    outv[2 * tid]     = make_float4(res[0], res[1], res[2], res[3]);
    outv[2 * tid + 1] = make_float4(res[4], res[5], res[6], res[7]);

    ((float4*)(out + 2 * E_NUM + 7 * P_NUM))[tid] =
        make_float4(ev.x - iev.x, ev.y - iev.y, ev.z - iev.z, ev.w - iev.w);
}

extern "C" void kernel_launch(void* const* d_in, const int* in_sizes, int n_in,
                              void* d_out, int out_size, void* d_ws, size_t ws_size,
                              hipStream_t stream) {
    const float* poses        = (const float*)d_in[0];
    const float* init_poses   = (const float*)d_in[1];
    const float* patch_coords = (const float*)d_in[2];
    const float* elev         = (const float*)d_in[3];
    const float* init_elev    = (const float*)d_in[4];
    const float* target       = (const float*)d_in[5];
    const int*   src_idx      = (const int*)d_in[6];
    const int*   tgt_idx      = (const int*)d_in[7];
    const int*   patch_idx    = (const int*)d_in[8];
    float*       out          = (float*)d_out;

    const size_t fused_bytes = (size_t)E_NUM * 16;
    const bool fused_ok = ws_size >= fused_bytes + (size_t)P_NUM * 32;
    float4* fused = (float4*)d_ws;
    float4* pose8 = (float4*)((char*)d_ws + (fused_ok ? fused_bytes : 0));

    pose_prep<<<(7 * P_NUM / 4) / 256, 256, 0, stream>>>(poses, init_poses, pose8, out);

    const int block = 256;
    const int grid  = E_NUM / (block * EPT);    // 4096
    if (fused_ok) {
        fuse_prep<<<(E_NUM / 4) / 256, 256, 0, stream>>>(patch_coords, elev, fused);
        ba_main<true><<<grid, block, 0, stream>>>(fused, patch_coords, elev, init_elev,
                                                  pose8, target, src_idx, tgt_idx,
                                                  patch_idx, out);
    } else {
        ba_main<false><<<grid, block, 0, stream>>>(fused, patch_coords, elev, init_elev,
                                                   pose8, target, src_idx, tgt_idx,
                                                   patch_idx, out);
    }
}

// Round 6
// 271.148 us; speedup vs baseline: 1.1660x; 1.0242x over previous
//
#include <hip/hip_runtime.h>
#include <math.h>

#define P_NUM 8192
#define E_NUM 4194304
#define EPT 4

#define FOV_H 2.0943951f

typedef float f32x4 __attribute__((ext_vector_type(4)));
typedef int   i32x4 __attribute__((ext_vector_type(4)));

// ---------- prep A: fused 16-B exact record (r,theta,elev,pad) + elev residual ----------
__global__ __launch_bounds__(256) void fuse_prep(const float* __restrict__ patch_coords,
                                                 const float* __restrict__ elev,
                                                 const float* __restrict__ init_elev,
                                                 f32x4* __restrict__ fused,
                                                 float* __restrict__ out) {
    const int tid = blockIdx.x * blockDim.x + threadIdx.x;   // [0, E_NUM/4)
    const f32x4 a  = __builtin_nontemporal_load((const f32x4*)patch_coords + 2 * tid);
    const f32x4 b  = __builtin_nontemporal_load((const f32x4*)patch_coords + 2 * tid + 1);
    const f32x4 e  = __builtin_nontemporal_load((const f32x4*)elev + tid);
    const f32x4 ie = __builtin_nontemporal_load((const f32x4*)init_elev + tid);

    // fused table: normal stores (L2 retention gives main a warm start)
    fused[4 * tid + 0] = (f32x4){a.x, a.y, e.x, 0.0f};
    fused[4 * tid + 1] = (f32x4){a.z, a.w, e.y, 0.0f};
    fused[4 * tid + 2] = (f32x4){b.x, b.y, e.z, 0.0f};
    fused[4 * tid + 3] = (f32x4){b.z, b.w, e.w, 0.0f};

    const f32x4 er = {e.x - ie.x, e.y - ie.y, e.z - ie.z, e.w - ie.w};
    __builtin_nontemporal_store(er, (f32x4*)(out + 2 * E_NUM + 7 * P_NUM) + tid);
}

// ---------- prep B: pad poses 7->8 floats + pose residual ----------
__global__ __launch_bounds__(256) void pose_prep(const float* __restrict__ poses,
                                                 const float* __restrict__ init_poses,
                                                 f32x4* __restrict__ pose8,
                                                 float* __restrict__ out) {
    const int tid = blockIdx.x * blockDim.x + threadIdx.x;   // [0, 14336)
    if (tid < P_NUM) {
        const float* s = poses + 7 * tid;
        pose8[2 * tid]     = (f32x4){s[0], s[1], s[2], s[3]};  // tx ty tz qx
        pose8[2 * tid + 1] = (f32x4){s[4], s[5], s[6], 0.0f};  // qy qz qw pad
    }
    if (tid < (7 * P_NUM) / 4) {
        const f32x4 a = ((const f32x4*)poses)[tid];
        const f32x4 b = ((const f32x4*)init_poses)[tid];
        const f32x4 r = {a.x - b.x, a.y - b.y, a.z - b.z, a.w - b.w};
        __builtin_nontemporal_store(r, (f32x4*)(out + 2 * E_NUM) + tid);
    }
}

__device__ __forceinline__ void quatrot(float ux, float uy, float uz, float uw,
                                        float vx, float vy, float vz,
                                        float& ox, float& oy, float& oz) {
    float tqx = 2.0f * (uy * vz - uz * vy);
    float tqy = 2.0f * (uz * vx - ux * vz);
    float tqz = 2.0f * (ux * vy - uy * vx);
    ox = vx + uw * tqx + (uy * tqz - uz * tqy);
    oy = vy + uw * tqy + (uz * tqx - ux * tqz);
    oz = vz + uw * tqz + (ux * tqy - uy * tqx);
}

__global__ __launch_bounds__(256) void ba_main(
    const f32x4* __restrict__ fused,   // E_NUM x (r,theta,elev,pad), ws
    const f32x4* __restrict__ pose8,   // ws
    const float* __restrict__ target,  // E_NUM*2
    const int*   __restrict__ src_idx,
    const int*   __restrict__ tgt_idx,
    const int*   __restrict__ patch_idx,
    float*       __restrict__ out)
{
    const int tid = blockIdx.x * blockDim.x + threadIdx.x;  // [0, E_NUM/EPT)

    const float R_RANGE = 30.0f - 0.5f;
    const float BINS    = 512.0f;
    const float BEAMS   = 512.0f;

    // streaming index loads: non-temporal (don't evict the gather table)
    const i32x4 s4 = __builtin_nontemporal_load((const i32x4*)src_idx + tid);
    const i32x4 t4 = __builtin_nontemporal_load((const i32x4*)tgt_idx + tid);
    const i32x4 p4 = __builtin_nontemporal_load((const i32x4*)patch_idx + tid);
    const int si[EPT] = {s4.x, s4.y, s4.z, s4.w};
    const int ti[EPT] = {t4.x, t4.y, t4.z, t4.w};
    const int pi[EPT] = {p4.x, p4.y, p4.z, p4.w};

    // ---- issue all gathers up front (cached: table + poses) ----
    f32x4 rec[EPT];
    f32x4 slo[EPT], shi[EPT], tlo[EPT], thi[EPT];
#pragma unroll
    for (int e = 0; e < EPT; ++e) {
        rec[e] = fused[pi[e]];
        slo[e] = pose8[2 * si[e]];
        shi[e] = pose8[2 * si[e] + 1];
        tlo[e] = pose8[2 * ti[e]];
        thi[e] = pose8[2 * ti[e] + 1];
    }

    const f32x4 tg01 = __builtin_nontemporal_load((const f32x4*)target + 2 * tid);
    const f32x4 tg23 = __builtin_nontemporal_load((const f32x4*)target + 2 * tid + 1);
    const float tgr[EPT]  = {tg01.x, tg01.z, tg23.x, tg23.z};
    const float tgth[EPT] = {tg01.y, tg01.w, tg23.y, tg23.w};

    float res[2 * EPT];
#pragma unroll
    for (int e = 0; e < EPT; ++e) {
        const float r  = rec[e].x;
        const float th = rec[e].y;
        const float ph = rec[e].z;
        const float cp = cosf(ph), sph = sinf(ph);
        const float ct = cosf(th), sth = sinf(th);
        float vx = r * cp * ct;
        float vy = r * cp * sth;
        float vz = r * sph;

        float gx, gy, gz;
        quatrot(slo[e].w, shi[e].x, shi[e].y, shi[e].z, vx, vy, vz, gx, gy, gz);
        gx += slo[e].x; gy += slo[e].y; gz += slo[e].z;

        float lx, ly, lz;
        quatrot(-tlo[e].w, -thi[e].x, -thi[e].y, thi[e].z,
                gx - tlo[e].x, gy - tlo[e].y, gz - tlo[e].z, lx, ly, lz);

        const float rr  = sqrtf(lx * lx + ly * ly + lz * lz);
        const float tth = atan2f(ly, lx);
        res[2 * e]     = (rr  - tgr[e])  / R_RANGE * BINS;
        res[2 * e + 1] = (tth - tgth[e]) / FOV_H * BEAMS;
    }

    const f32x4 o0 = {res[0], res[1], res[2], res[3]};
    const f32x4 o1 = {res[4], res[5], res[6], res[7]};
    __builtin_nontemporal_store(o0, (f32x4*)out + 2 * tid);
    __builtin_nontemporal_store(o1, (f32x4*)out + 2 * tid + 1);
}

extern "C" void kernel_launch(void* const* d_in, const int* in_sizes, int n_in,
                              void* d_out, int out_size, void* d_ws, size_t ws_size,
                              hipStream_t stream) {
    const float* poses        = (const float*)d_in[0];
    const float* init_poses   = (const float*)d_in[1];
    const float* patch_coords = (const float*)d_in[2];
    const float* elev         = (const float*)d_in[3];
    const float* init_elev    = (const float*)d_in[4];
    const float* target       = (const float*)d_in[5];
    const int*   src_idx      = (const int*)d_in[6];
    const int*   tgt_idx      = (const int*)d_in[7];
    const int*   patch_idx    = (const int*)d_in[8];
    float*       out          = (float*)d_out;

    f32x4* fused = (f32x4*)d_ws;                                   // 67.1 MB
    f32x4* pose8 = (f32x4*)((char*)d_ws + (size_t)E_NUM * 16);     // 256 KB

    pose_prep<<<(7 * P_NUM / 4) / 256, 256, 0, stream>>>(poses, init_poses, pose8, out);
    fuse_prep<<<(E_NUM / 4) / 256, 256, 0, stream>>>(patch_coords, elev, init_elev,
                                                     fused, out);

    const int block = 256;
    const int grid  = E_NUM / (block * EPT);    // 4096
    ba_main<<<grid, block, 0, stream>>>(fused, pose8, target, src_idx, tgt_idx,
                                        patch_idx, out);
}